// Round 7
// baseline (246.773 us; speedup 1.0000x reference)
//
#include <hip/hip_runtime.h>
#include <cmath>

#define BB 8
#define LL 512
#define HH 512

typedef __attribute__((ext_vector_type(8))) short short8;
typedef __attribute__((ext_vector_type(4))) float floatx4;

#define MM __builtin_amdgcn_mfma_f32_16x16x32_bf16
#define SB() __builtin_amdgcn_sched_barrier(0)

__device__ __forceinline__ unsigned short f2bf(float x) {
  unsigned int u = __float_as_uint(x);
  unsigned int r = (u + 0x7fffu + ((u >> 16) & 1u)) >> 16;
  return (unsigned short)r;
}

// ---------------- kP1: fused per-row prep ----------------
// One wave per row of {A, Bm, C} (12288 rows). Each input row read ONCE.
__global__ __launch_bounds__(256) void kP1(
    const float* __restrict__ A, const float* __restrict__ Bm, const float* __restrict__ C,
    const float* __restrict__ w0, const float* __restrict__ w1, const float* __restrict__ w2,
    unsigned short* __restrict__ Xm0, unsigned short* __restrict__ Xm1,
    unsigned short* __restrict__ Xm2,
    unsigned short* __restrict__ Bn, unsigned short* __restrict__ Cn,
    float* __restrict__ rowterm, float* __restrict__ colterm) {
  int tid = threadIdx.x;
  int wave = blockIdx.x * 4 + (tid >> 6);   // 0..12287
  int lane = tid & 63;
  int m = wave >> 12;
  int rem = wave & 4095;                    // b*512 + i
  int b = rem >> 9, i = rem & 511;
  const float* src = (m == 0) ? A : (m == 1 ? Bm : C);
  const float* rp = src + (size_t)rem * HH + lane * 8;
  float4 xa = *(const float4*)rp, xb = *(const float4*)(rp + 4);
  float x[8] = {xa.x, xa.y, xa.z, xa.w, xb.x, xb.y, xb.z, xb.w};

  const float *wva, *wvb;
  float *da, *db;
  if (m == 0) {
    wva = w0;      wvb = w1;
    da = rowterm + (0 * BB + b) * LL + i;  db = rowterm + (1 * BB + b) * LL + i;
  } else if (m == 1) {
    wva = w0 + HH; wvb = w2;
    da = colterm + (0 * BB + b) * LL + i;  db = rowterm + (2 * BB + b) * LL + i;
  } else {
    wva = w1 + HH; wvb = w2 + HH;
    da = colterm + (1 * BB + b) * LL + i;  db = colterm + (2 * BB + b) * LL + i;
  }
  const float* ap1 = wva + lane * 8;
  const float* bp1 = wvb + lane * 8;
  float4 wa1 = *(const float4*)ap1, wa2 = *(const float4*)(ap1 + 4);
  float4 wb1 = *(const float4*)bp1, wb2 = *(const float4*)(bp1 + 4);
  float wa[8] = {wa1.x, wa1.y, wa1.z, wa1.w, wa2.x, wa2.y, wa2.z, wa2.w};
  float wb[8] = {wb1.x, wb1.y, wb1.z, wb1.w, wb2.x, wb2.y, wb2.z, wb2.w};
  float a1 = 0.f, a2 = 0.f;
#pragma unroll
  for (int e = 0; e < 8; ++e) { a1 += x[e] * wa[e]; a2 += x[e] * wb[e]; }
#pragma unroll
  for (int off = 32; off; off >>= 1) {
    a1 += __shfl_xor(a1, off, 64);
    a2 += __shfl_xor(a2, off, 64);
  }
  if (lane == 0) { *da = a1; *db = a2; }

  size_t oo = (size_t)rem * HH + lane * 8;
  if (m == 0) {
    const float* m0 = w0 + 2 * HH + lane * 8;
    const float* m1 = w1 + 2 * HH + lane * 8;
    float4 ma1 = *(const float4*)m0, ma2 = *(const float4*)(m0 + 4);
    float4 mb1 = *(const float4*)m1, mb2 = *(const float4*)(m1 + 4);
    float wm0[8] = {ma1.x, ma1.y, ma1.z, ma1.w, ma2.x, ma2.y, ma2.z, ma2.w};
    float wm1[8] = {mb1.x, mb1.y, mb1.z, mb1.w, mb2.x, mb2.y, mb2.z, mb2.w};
    short8 o0, o1;
#pragma unroll
    for (int e = 0; e < 8; ++e) { o0[e] = (short)f2bf(x[e] * wm0[e]); o1[e] = (short)f2bf(x[e] * wm1[e]); }
    *(short8*)(Xm0 + oo) = o0;
    *(short8*)(Xm1 + oo) = o1;
  } else if (m == 1) {
    const float* m2 = w2 + 2 * HH + lane * 8;
    float4 mc1 = *(const float4*)m2, mc2 = *(const float4*)(m2 + 4);
    float wm2[8] = {mc1.x, mc1.y, mc1.z, mc1.w, mc2.x, mc2.y, mc2.z, mc2.w};
    short8 on, o2;
#pragma unroll
    for (int e = 0; e < 8; ++e) { on[e] = (short)f2bf(x[e]); o2[e] = (short)f2bf(x[e] * wm2[e]); }
    *(short8*)(Bn + oo) = on;
    *(short8*)(Xm2 + oo) = o2;
  } else {
    short8 on;
#pragma unroll
    for (int e = 0; e < 8; ++e) on[e] = (short)f2bf(x[e]);
    *(short8*)(Cn + oo) = on;
  }
}

// ---------------- k0t: bf16 transpose (Bn->Bt, Cn->Ct), 64x64 tiles ----------------
__global__ __launch_bounds__(256) void k0t(
    const unsigned short* __restrict__ Bn, const unsigned short* __restrict__ Cn,
    unsigned short* __restrict__ Bt, unsigned short* __restrict__ Ct) {
  __shared__ unsigned short tile[64][68];
  int bid = blockIdx.x;            // 1024
  int s = bid >> 9;
  int rem = bid & 511;
  int b = rem >> 6, tr = (rem >> 3) & 7, tc = rem & 7;
  const unsigned short* src = s ? Cn : Bn;
  unsigned short* dt = s ? Ct : Bt;
  int t = threadIdx.x;
#pragma unroll
  for (int h = 0; h < 2; ++h) {
    int id = h * 256 + t;
    int row = id >> 3, c8 = id & 7;
    short8 v = *(const short8*)(src + ((size_t)(b * 512 + tr * 64 + row)) * 512 + tc * 64 + c8 * 8);
    *(short8*)&tile[row][c8 * 8] = v;
  }
  __syncthreads();
  int d = t >> 2, jc = t & 3;
  short8 v0, v1;
#pragma unroll
  for (int e = 0; e < 8; ++e) v0[e] = (short)tile[jc * 16 + e][d];
#pragma unroll
  for (int e = 0; e < 8; ++e) v1[e] = (short)tile[jc * 16 + 8 + e][d];
  unsigned short* tp = dt + ((size_t)(b * 512 + tc * 64 + d)) * 512 + tr * 64 + jc * 16;
  *(short8*)tp = v0;
  *(short8*)(tp + 8) = v1;
}

// ---------------- K2: fused MFMA pair-attention, 32-row tiles ----------------
// 384 blocks (= 8 XCD x 48, 3 (p,b) Y-sets per XCD L2) x 512 threads.
// 32KB LDS (A/P alias) + VGPR cap 128 (__launch_bounds__(512,4)) -> 2 blocks/CU
// co-resident: fixes the R6 grid-starved occupancy (192 blocks on 256 CUs,
// 16% occupancy, 64 idle CUs). Ring-pipelined K-loops pinned with sched_barrier.
__global__ __launch_bounds__(512, 4) void k2_mfma(
    const unsigned short* __restrict__ Xm0, const unsigned short* __restrict__ Xm1,
    const unsigned short* __restrict__ Xm2,
    const unsigned short* __restrict__ Bn, const unsigned short* __restrict__ Cn,
    const unsigned short* __restrict__ Bt, const unsigned short* __restrict__ Ct,
    const float* __restrict__ A, const float* __restrict__ Bm,
    const float* __restrict__ rowterm, const float* __restrict__ colterm,
    float* __restrict__ mrow, float* __restrict__ out) {
  __shared__ __align__(16) unsigned char smem[32768];
  unsigned short* A_lds = (unsigned short*)smem;        // phase1: 32x512 bf16 swizzled
  unsigned short* P_lds = (unsigned short*)smem;        // phase2: 32x512 bf16 swizzled
  float* sm_m = (float*)smem;                            // softmax: 8x32 (aliases, fenced)
  float* sm_l = (float*)(smem + 1024);                   // softmax: 8x32

  int tid = threadIdx.x;
  int bid0 = blockIdx.x;
  // bijective XCD remap: xcd = bid0&7 owns 48 consecutive logical blocks
  // = 3 full (p,b) groups of 16 row-blocks -> 3MB Yn+Yt resident per XCD L2.
  int bid = (bid0 & 7) * 48 + (bid0 >> 3);
  int p = bid >> 7;            // 3
  int rem = bid & 127;
  int b = rem >> 4;            // 8
  int rb = rem & 15;           // 16 row-blocks of 32
  int i0 = rb * 32;

  const unsigned short* Xmp = (p == 0) ? Xm0 : ((p == 1) ? Xm1 : Xm2);
  const unsigned short* Yn  = (p == 0) ? Bn : Cn;
  const unsigned short* Yt  = (p == 0) ? Bt : Ct;
  const float* X = (p == 2) ? Bm : A;

  int wc = tid >> 6;           // wave 0..7 -> 64-col slice
  int lane = tid & 63;
  int n16 = lane & 15, q = lane >> 4;
  int e8 = n16 & 7;

  // ---- Stage Xm rows i0..i0+31 into LDS, coalesced, chunk-XOR swizzled ----
#pragma unroll
  for (int j = 0; j < 4; ++j) {
    int idx = j * 512 + tid;
    int row = idx >> 6;          // 0..31
    int cc = idx & 63;
    short8 v = *(const short8*)(Xmp + ((size_t)(b * LL + i0 + row)) * HH + cc * 8);
    *(short8*)&A_lds[row * 512 + (cc ^ (row & 7)) * 8] = v;
  }
  __syncthreads();

  const unsigned short* br0 = Yn + ((size_t)(b * LL + wc * 64 + n16)) * HH + q * 8;
  const unsigned short* br1 = br0 + 16 * HH;
  const unsigned short* br2 = br0 + 32 * HH;
  const unsigned short* br3 = br0 + 48 * HH;

  floatx4 acc[2][4] = {};
  short8 Ax0[2], Ax1[2], Bx0[4], Bx1[4], Bx2[4];

#define LA(AF, kk) do { int ch_ = (((kk) * 4 + q) ^ e8) * 8; \
    AF[0] = *(const short8*)&A_lds[(n16)      * 512 + ch_]; \
    AF[1] = *(const short8*)&A_lds[(16 + n16) * 512 + ch_]; } while (0)
#define LB1(BF, kk) do { const int k0_ = (kk) * 32; \
    BF[0] = *(const short8*)(br0 + k0_); \
    BF[1] = *(const short8*)(br1 + k0_); \
    BF[2] = *(const short8*)(br2 + k0_); \
    BF[3] = *(const short8*)(br3 + k0_); } while (0)
#define MF1(AF, BF) do { \
    acc[0][0]=MM(AF[0],BF[0],acc[0][0],0,0,0); acc[0][1]=MM(AF[0],BF[1],acc[0][1],0,0,0); \
    acc[0][2]=MM(AF[0],BF[2],acc[0][2],0,0,0); acc[0][3]=MM(AF[0],BF[3],acc[0][3],0,0,0); \
    acc[1][0]=MM(AF[1],BF[0],acc[1][0],0,0,0); acc[1][1]=MM(AF[1],BF[1],acc[1][1],0,0,0); \
    acc[1][2]=MM(AF[1],BF[2],acc[1][2],0,0,0); acc[1][3]=MM(AF[1],BF[3],acc[1][3],0,0,0); } while (0)

  LB1(Bx0, 0); LB1(Bx1, 1); LB1(Bx2, 2); LA(Ax0, 0); LA(Ax1, 1); SB();
  MF1(Ax0, Bx0); LA(Ax0, 2);  LB1(Bx0, 3);  SB();
  MF1(Ax1, Bx1); LA(Ax1, 3);  LB1(Bx1, 4);  SB();
  MF1(Ax0, Bx2); LA(Ax0, 4);  LB1(Bx2, 5);  SB();
  MF1(Ax1, Bx0); LA(Ax1, 5);  LB1(Bx0, 6);  SB();
  MF1(Ax0, Bx1); LA(Ax0, 6);  LB1(Bx1, 7);  SB();
  MF1(Ax1, Bx2); LA(Ax1, 7);  LB1(Bx2, 8);  SB();
  MF1(Ax0, Bx0); LA(Ax0, 8);  LB1(Bx0, 9);  SB();
  MF1(Ax1, Bx1); LA(Ax1, 9);  LB1(Bx1, 10); SB();
  MF1(Ax0, Bx2); LA(Ax0, 10); LB1(Bx2, 11); SB();
  MF1(Ax1, Bx0); LA(Ax1, 11); LB1(Bx0, 12); SB();
  MF1(Ax0, Bx1); LA(Ax0, 12); LB1(Bx1, 13); SB();
  MF1(Ax1, Bx2); LA(Ax1, 13); LB1(Bx2, 14); SB();
  MF1(Ax0, Bx0); LA(Ax0, 14); LB1(Bx0, 15); SB();
  MF1(Ax1, Bx1); LA(Ax1, 15); SB();
  MF1(Ax0, Bx2); SB();
  MF1(Ax1, Bx0);
#undef LA
#undef LB1
#undef MF1

  __syncthreads();   // all A_lds reads done -> sm region may be written

  // ---- Softmax over 32 rows: per-wave stats + 8-wave LDS combine ----
  float rtv[2][4], ctv[4], mh[2][4], ml[2][4], rinv[2][4];
  {
    const float* rtp = rowterm + (p * BB + b) * LL + i0 + q * 4;
#pragma unroll
    for (int rt = 0; rt < 2; ++rt)
#pragma unroll
      for (int r = 0; r < 4; ++r) rtv[rt][r] = rtp[rt * 16 + r];
    const float* ctp = colterm + (p * BB + b) * LL + wc * 64 + n16;
#pragma unroll
    for (int f = 0; f < 4; ++f) ctv[f] = ctp[f * 16];
  }
#pragma unroll
  for (int rt = 0; rt < 2; ++rt)
#pragma unroll
    for (int r = 0; r < 4; ++r) {
      float m = -1e30f;
#pragma unroll
      for (int f = 0; f < 4; ++f) {
        float v = acc[rt][f][r] + rtv[rt][r] + ctv[f];
        acc[rt][f][r] = v;
        m = fmaxf(m, v);
      }
      m = fmaxf(m, __shfl_xor(m, 1, 64));
      m = fmaxf(m, __shfl_xor(m, 2, 64));
      m = fmaxf(m, __shfl_xor(m, 4, 64));
      m = fmaxf(m, __shfl_xor(m, 8, 64));
      mh[rt][r] = m;
    }
  if (n16 == 0) {
#pragma unroll
    for (int rt = 0; rt < 2; ++rt)
#pragma unroll
      for (int r = 0; r < 4; ++r) sm_m[wc * 32 + rt * 16 + q * 4 + r] = mh[rt][r];
  }
  __syncthreads();
#pragma unroll
  for (int rt = 0; rt < 2; ++rt)
#pragma unroll
    for (int r = 0; r < 4; ++r) {
      float m = mh[rt][r];
#pragma unroll
      for (int k = 0; k < 8; ++k) m = fmaxf(m, sm_m[k * 32 + rt * 16 + q * 4 + r]);
      mh[rt][r] = m;
      float l = 0.f;
#pragma unroll
      for (int f = 0; f < 4; ++f) {
        float pv = __expf(acc[rt][f][r] - m);
        acc[rt][f][r] = pv;
        l += pv;
      }
      l += __shfl_xor(l, 1, 64);
      l += __shfl_xor(l, 2, 64);
      l += __shfl_xor(l, 4, 64);
      l += __shfl_xor(l, 8, 64);
      ml[rt][r] = l;
    }
  if (n16 == 0) {
#pragma unroll
    for (int rt = 0; rt < 2; ++rt)
#pragma unroll
      for (int r = 0; r < 4; ++r) sm_l[wc * 32 + rt * 16 + q * 4 + r] = ml[rt][r];
    if (wc == 0) {
#pragma unroll
      for (int rt = 0; rt < 2; ++rt)
#pragma unroll
        for (int r = 0; r < 4; ++r)
          mrow[(p * BB + b) * LL + i0 + rt * 16 + q * 4 + r] = mh[rt][r];
    }
  }
  __syncthreads();
#pragma unroll
  for (int rt = 0; rt < 2; ++rt)
#pragma unroll
    for (int r = 0; r < 4; ++r) {
      float lf = 0.f;
#pragma unroll
      for (int k = 0; k < 8; ++k) lf += sm_l[k * 32 + rt * 16 + q * 4 + r];
      rinv[rt][r] = 1.f / lf;
    }
  __syncthreads();   // all sm_l reads done -> P may overwrite the region

  // ---- P -> LDS (bf16, unnormalized, XOR-swizzled 8-short chunks) ----
#pragma unroll
  for (int f = 0; f < 4; ++f) {
    int c = wc * 8 + f * 2 + (n16 >> 3);
#pragma unroll
    for (int rt = 0; rt < 2; ++rt)
#pragma unroll
      for (int r = 0; r < 4; ++r) {
        int row = rt * 16 + q * 4 + r;
        int pc = c ^ (row & 7);
        P_lds[row * 512 + pc * 8 + e8] = f2bf(acc[rt][f][r]);
      }
  }
  __syncthreads();

  // ---- Phase 2: O[32 x 512] = P @ Y (B from Yt), same pipelined schedule ----
  const unsigned short* tr0 = Yt + ((size_t)(b * LL + wc * 64 + n16)) * HH + q * 8;
  const unsigned short* tr1 = tr0 + 16 * HH;
  const unsigned short* tr2 = tr0 + 32 * HH;
  const unsigned short* tr3 = tr0 + 48 * HH;

  floatx4 oacc[2][4] = {};
  short8 Px0[2], Px1[2], By0[4], By1[4], By2[4];

#define LP(PF, kj) do { int ch_ = (((kj) * 4 + q) ^ e8) * 8; \
    PF[0] = *(const short8*)&P_lds[(n16)      * 512 + ch_]; \
    PF[1] = *(const short8*)&P_lds[(16 + n16) * 512 + ch_]; } while (0)
#define LB2(BF, kj) do { const int j0_ = (kj) * 32; \
    BF[0] = *(const short8*)(tr0 + j0_); \
    BF[1] = *(const short8*)(tr1 + j0_); \
    BF[2] = *(const short8*)(tr2 + j0_); \
    BF[3] = *(const short8*)(tr3 + j0_); } while (0)
#define MF2(PF, BF) do { \
    oacc[0][0]=MM(PF[0],BF[0],oacc[0][0],0,0,0); oacc[0][1]=MM(PF[0],BF[1],oacc[0][1],0,0,0); \
    oacc[0][2]=MM(PF[0],BF[2],oacc[0][2],0,0,0); oacc[0][3]=MM(PF[0],BF[3],oacc[0][3],0,0,0); \
    oacc[1][0]=MM(PF[1],BF[0],oacc[1][0],0,0,0); oacc[1][1]=MM(PF[1],BF[1],oacc[1][1],0,0,0); \
    oacc[1][2]=MM(PF[1],BF[2],oacc[1][2],0,0,0); oacc[1][3]=MM(PF[1],BF[3],oacc[1][3],0,0,0); } while (0)

  LB2(By0, 0); LB2(By1, 1); LB2(By2, 2); LP(Px0, 0); LP(Px1, 1); SB();
  MF2(Px0, By0); LP(Px0, 2);  LB2(By0, 3);  SB();
  MF2(Px1, By1); LP(Px1, 3);  LB2(By1, 4);  SB();
  MF2(Px0, By2); LP(Px0, 4);  LB2(By2, 5);  SB();
  MF2(Px1, By0); LP(Px1, 5);  LB2(By0, 6);  SB();
  MF2(Px0, By1); LP(Px0, 6);  LB2(By1, 7);  SB();
  MF2(Px1, By2); LP(Px1, 7);  LB2(By2, 8);  SB();
  MF2(Px0, By0); LP(Px0, 8);  LB2(By0, 9);  SB();
  MF2(Px1, By1); LP(Px1, 9);  LB2(By1, 10); SB();
  MF2(Px0, By2); LP(Px0, 10); LB2(By2, 11); SB();
  MF2(Px1, By0); LP(Px1, 11); LB2(By0, 12); SB();
  MF2(Px0, By1); LP(Px0, 12); LB2(By1, 13); SB();
  MF2(Px1, By2); LP(Px1, 13); LB2(By2, 14); SB();
  MF2(Px0, By0); LP(Px0, 14); LB2(By0, 15); SB();
  MF2(Px1, By1); LP(Px1, 15); SB();
  MF2(Px0, By2); SB();
  MF2(Px1, By0);
#undef LP
#undef LB2
#undef MF2

  // ---- Epilogue (a2b + product slices only; copies live in k4) ----
  int secoff, colbase;
  if      (p == 0) { secoff = 0;   colbase = 512;  }
  else if (p == 1) { secoff = 0;   colbase = 1024; }
  else             { secoff = 512; colbase = 1024; }

#pragma unroll
  for (int f = 0; f < 4; ++f) {
    int d = wc * 64 + f * 16 + n16;
#pragma unroll
    for (int rt = 0; rt < 2; ++rt)
#pragma unroll
      for (int r = 0; r < 4; ++r) {
        int ig = i0 + rt * 16 + q * 4 + r;
        float val = oacc[rt][f][r] * rinv[rt][r];
        size_t ob = ((size_t)b * 1536 + secoff + ig) * 2560;
        out[ob + colbase + d] = val;
        out[ob + colbase + 1024 + d] = X[((size_t)b * LL + ig) * HH + d] * val;
      }
  }
}

// ---------------- K3: beta softmax + weighted row-sum (192 blocks x 512) ----------------
__global__ __launch_bounds__(512) void k3_beta(
    const float* __restrict__ A, const float* __restrict__ Bm,
    const float* __restrict__ mrow, float* __restrict__ vvec) {
  __shared__ float red[512];
  __shared__ float beta[LL];
  __shared__ float s_inv;
  int blk = blockIdx.x;           // 192
  int p = blk >> 6;
  int rem2 = blk & 63;
  int b = rem2 >> 3;
  int dch = rem2 & 7;
  int tid = threadIdx.x;          // 0..511
  const float* m = mrow + (p * BB + b) * LL;
  red[tid] = m[tid];
  __syncthreads();
  for (int off = 256; off; off >>= 1) {
    if (tid < off) red[tid] = fmaxf(red[tid], red[tid + off]);
    __syncthreads();
  }
  float mx = red[0];
  __syncthreads();
  float e0 = __expf(m[tid] - mx);
  beta[tid] = e0;
  red[tid] = e0;
  __syncthreads();
  for (int off = 256; off; off >>= 1) {
    if (tid < off) red[tid] += red[tid + off];
    __syncthreads();
  }
  if (tid == 0) s_inv = 1.f / red[0];
  __syncthreads();
  const float* Xb = ((p == 2) ? Bm : A) + (size_t)b * LL * HH;
  int d = dch * 64 + (tid & 63);
  int ig = tid >> 6;              // 8 groups of 64 rows
  float acc = 0.f;
#pragma unroll 4
  for (int i2 = ig * 64; i2 < ig * 64 + 64; ++i2)
    acc += beta[i2] * Xb[(size_t)i2 * HH + d];
  red[tid] = acc;
  __syncthreads();
  if (tid < 64) {
    float s = 0.f;
#pragma unroll
    for (int k = 0; k < 8; ++k) s += red[tid + k * 64];
    vvec[(p * BB + b) * HH + dch * 64 + tid] = s * s_inv;
  }
}

// ---------------- K4: finalize (9 slices incl. copies), float4 full-line writes ----------------
__global__ __launch_bounds__(256) void k4_finalize(
    const float* __restrict__ A, const float* __restrict__ Bm, const float* __restrict__ C,
    const float* __restrict__ vvec, float* __restrict__ out) {
  unsigned int idx = blockIdx.x * 256 + threadIdx.x;   // 4718592 threads
  int f4 = idx & 127;
  int i  = (idx >> 7) & 511;
  unsigned int ub = idx >> 16;
  unsigned int u = ub % 9;
  unsigned int b = ub / 9;
  int sec, slice;
  if (u == 0)      { sec = 0; slice = 0; }
  else if (u <= 3) { sec = 1; slice = (u == 1) ? 0 : (u == 2 ? 1 : 3); }
  else             { sec = 2; slice = (int)u - 4; }
  int cc = f4 * 4;
  const float* enc = sec == 0 ? A : (sec == 1 ? Bm : C);
  float4 val;
  if (slice == 0) {
    val = *(const float4*)(enc + ((size_t)b * LL + i) * HH + cc);
  } else {
    int vp = (sec == 1) ? 0 : ((slice == 1 || slice == 3) ? 1 : 2);
    float4 v = *(const float4*)(vvec + (vp * BB + b) * HH + cc);
    if (slice <= 2) {
      val = v;
    } else {
      float4 e = *(const float4*)(enc + ((size_t)b * LL + i) * HH + cc);
      val.x = e.x * v.x; val.y = e.y * v.y; val.z = e.z * v.z; val.w = e.w * v.w;
    }
  }
  *(float4*)(out + ((size_t)b * 1536 + sec * 512 + i) * 2560 + slice * 512 + cc) = val;
}

extern "C" void kernel_launch(void* const* d_in, const int* in_sizes, int n_in,
                              void* d_out, int out_size, void* d_ws, size_t ws_size,
                              hipStream_t stream) {
  const float* A  = (const float*)d_in[0];
  const float* Bm = (const float*)d_in[1];
  const float* C  = (const float*)d_in[2];
  const float* w0 = (const float*)d_in[3];
  const float* w1 = (const float*)d_in[4];
  const float* w2 = (const float*)d_in[5];
  float* out = (float*)d_out;

  float* wsf = (float*)d_ws;
  float* rowterm = wsf;
  float* colterm = wsf + 12288;
  float* mrow    = wsf + 24576;
  float* vvec    = wsf + 36864;
  unsigned short* wss = (unsigned short*)(wsf + 49152);
  const size_t MSZ = (size_t)BB * LL * HH;     // 2,097,152
  unsigned short* Bn  = wss;
  unsigned short* Cn  = wss + MSZ;
  unsigned short* Bt  = wss + 2 * MSZ;
  unsigned short* Ct  = wss + 3 * MSZ;
  unsigned short* Xm0 = wss + 4 * MSZ;
  unsigned short* Xm1 = wss + 5 * MSZ;
  unsigned short* Xm2 = wss + 6 * MSZ;

  kP1<<<3072, 256, 0, stream>>>(A, Bm, C, w0, w1, w2, Xm0, Xm1, Xm2, Bn, Cn,
                                rowterm, colterm);
  k0t<<<1024, 256, 0, stream>>>(Bn, Cn, Bt, Ct);
  k2_mfma<<<384, 512, 0, stream>>>(Xm0, Xm1, Xm2, Bn, Cn, Bt, Ct, A, Bm,
                                   rowterm, colterm, mrow, out);
  k3_beta<<<192, 512, 0, stream>>>(A, Bm, mrow, vvec);
  k4_finalize<<<18432, 256, 0, stream>>>(A, Bm, C, vvec, out);
}

// Round 9
// 214.592 us; speedup vs baseline: 1.1500x; 1.1500x over previous
//
#include <hip/hip_runtime.h>
#include <cmath>

#define BB 8
#define LL 512
#define HH 512

typedef __attribute__((ext_vector_type(8))) short short8;
typedef __attribute__((ext_vector_type(4))) float floatx4;

#define MM __builtin_amdgcn_mfma_f32_16x16x32_bf16
#define SB() __builtin_amdgcn_sched_barrier(0)

__device__ __forceinline__ unsigned short f2bf(float x) {
  unsigned int u = __float_as_uint(x);
  unsigned int r = (u + 0x7fffu + ((u >> 16) & 1u)) >> 16;
  return (unsigned short)r;
}

// ---------------- kP2: fused prep (convert + dots + transpose) ----------------
// 192 blocks x 512 threads; block = 64-row stripe of one matrix {A,Bm,C}.
// Each input row read ONCE. m>=1 stages bf16 in a 64KB XOR-swizzled LDS tile
// (chunk ^= row&7 -- same scheme as k2's A_lds; no padding needed) and writes
// Bt/Ct with k0t's verified store pattern (16 rows x 128B contiguous per wave).
__global__ __launch_bounds__(512) void kP2(
    const float* __restrict__ A, const float* __restrict__ Bm, const float* __restrict__ C,
    const float* __restrict__ w0, const float* __restrict__ w1, const float* __restrict__ w2,
    unsigned short* __restrict__ Xm0, unsigned short* __restrict__ Xm1,
    unsigned short* __restrict__ Xm2,
    unsigned short* __restrict__ Bn, unsigned short* __restrict__ Cn,
    unsigned short* __restrict__ Bt, unsigned short* __restrict__ Ct,
    float* __restrict__ rowterm, float* __restrict__ colterm) {
  __shared__ unsigned short tile[8][64][64];   // exactly 64KB, chunk-XOR swizzled

  int bid = blockIdx.x;          // 192 = 3 matrices x 8 batches x 8 stripes
  int m = bid >> 6;
  int rem = bid & 63;
  int b = rem >> 3, rb = rem & 7;
  int i0 = rb * 64;
  int tid = threadIdx.x;
  int w = tid >> 6;              // wave 0..7 -> rows w*8 .. w*8+7 of stripe
  int lane = tid & 63;

  const float* src = (m == 0) ? A : (m == 1 ? Bm : C);
  const float *wva, *wvb;
  float *da, *db;
  if (m == 0) {
    wva = w0;      wvb = w1;
    da = rowterm + (0 * BB + b) * LL;  db = rowterm + (1 * BB + b) * LL;
  } else if (m == 1) {
    wva = w0 + HH; wvb = w2;
    da = colterm + (0 * BB + b) * LL;  db = rowterm + (2 * BB + b) * LL;
  } else {
    wva = w1 + HH; wvb = w2 + HH;
    da = colterm + (1 * BB + b) * LL;  db = colterm + (2 * BB + b) * LL;
  }

  float wa[8], wb[8], wmA[8], wmB[8];
  {
    const float* ap1 = wva + lane * 8;
    const float* bp1 = wvb + lane * 8;
    float4 t0 = *(const float4*)ap1, t1 = *(const float4*)(ap1 + 4);
    float4 t2 = *(const float4*)bp1, t3 = *(const float4*)(bp1 + 4);
    wa[0]=t0.x; wa[1]=t0.y; wa[2]=t0.z; wa[3]=t0.w; wa[4]=t1.x; wa[5]=t1.y; wa[6]=t1.z; wa[7]=t1.w;
    wb[0]=t2.x; wb[1]=t2.y; wb[2]=t2.z; wb[3]=t2.w; wb[4]=t3.x; wb[5]=t3.y; wb[6]=t3.z; wb[7]=t3.w;
  }
  if (m == 0) {
    const float* m0 = w0 + 2 * HH + lane * 8;
    const float* m1 = w1 + 2 * HH + lane * 8;
    float4 t0 = *(const float4*)m0, t1 = *(const float4*)(m0 + 4);
    float4 t2 = *(const float4*)m1, t3 = *(const float4*)(m1 + 4);
    wmA[0]=t0.x; wmA[1]=t0.y; wmA[2]=t0.z; wmA[3]=t0.w; wmA[4]=t1.x; wmA[5]=t1.y; wmA[6]=t1.z; wmA[7]=t1.w;
    wmB[0]=t2.x; wmB[1]=t2.y; wmB[2]=t2.z; wmB[3]=t2.w; wmB[4]=t3.x; wmB[5]=t3.y; wmB[6]=t3.z; wmB[7]=t3.w;
  } else if (m == 1) {
    const float* m2 = w2 + 2 * HH + lane * 8;
    float4 t0 = *(const float4*)m2, t1 = *(const float4*)(m2 + 4);
    wmA[0]=t0.x; wmA[1]=t0.y; wmA[2]=t0.z; wmA[3]=t0.w; wmA[4]=t1.x; wmA[5]=t1.y; wmA[6]=t1.z; wmA[7]=t1.w;
  }

  int tc = lane >> 3, c8 = lane & 7;   // sub-tile / chunk for LDS staging

#pragma unroll 2
  for (int rr = 0; rr < 8; ++rr) {
    int ro = w * 8 + rr;               // row within stripe
    int i = i0 + ro;                   // global row
    const float* rp = src + ((size_t)(b * 512 + i)) * HH + lane * 8;
    float4 xa = *(const float4*)rp, xb = *(const float4*)(rp + 4);
    float x[8] = {xa.x, xa.y, xa.z, xa.w, xb.x, xb.y, xb.z, xb.w};

    float a1 = 0.f, a2 = 0.f;
#pragma unroll
    for (int e = 0; e < 8; ++e) { a1 += x[e] * wa[e]; a2 += x[e] * wb[e]; }
#pragma unroll
    for (int off = 32; off; off >>= 1) {
      a1 += __shfl_xor(a1, off, 64);
      a2 += __shfl_xor(a2, off, 64);
    }
    if (lane == 0) { da[i] = a1; db[i] = a2; }

    size_t oo = ((size_t)(b * 512 + i)) * HH + lane * 8;
    if (m == 0) {
      short8 o0, o1;
#pragma unroll
      for (int e = 0; e < 8; ++e) { o0[e] = (short)f2bf(x[e] * wmA[e]); o1[e] = (short)f2bf(x[e] * wmB[e]); }
      *(short8*)(Xm0 + oo) = o0;
      *(short8*)(Xm1 + oo) = o1;
    } else if (m == 1) {
      short8 on, o2;
#pragma unroll
      for (int e = 0; e < 8; ++e) { on[e] = (short)f2bf(x[e]); o2[e] = (short)f2bf(x[e] * wmA[e]); }
      *(short8*)(Bn + oo) = on;
      *(short8*)(Xm2 + oo) = o2;
      *(short8*)&tile[tc][ro][(c8 ^ (ro & 7)) * 8] = on;
    } else {
      short8 on;
#pragma unroll
      for (int e = 0; e < 8; ++e) on[e] = (short)f2bf(x[e]);
      *(short8*)(Cn + oo) = on;
      *(short8*)&tile[tc][ro][(c8 ^ (ro & 7)) * 8] = on;
    }
  }

  if (m >= 1) {                        // block-uniform branch
    __syncthreads();
    unsigned short* dt = (m == 1) ? Bt : Ct;
    int tsub = tid >> 8;               // 0..1
    int tt = tid & 255;
    int d = tt >> 2, jc = tt & 3;      // col-in-subtile, 16-row group
#pragma unroll
    for (int p2 = 0; p2 < 4; ++p2) {
      int tcs = p2 * 2 + tsub;         // sub-tile 0..7
      short8 v0, v1;
#pragma unroll
      for (int e = 0; e < 8; ++e)
        v0[e] = (short)tile[tcs][jc * 16 + e][((d >> 3) ^ e) * 8 + (d & 7)];
#pragma unroll
      for (int e = 0; e < 8; ++e)
        v1[e] = (short)tile[tcs][jc * 16 + 8 + e][((d >> 3) ^ e) * 8 + (d & 7)];
      unsigned short* tp = dt + ((size_t)(b * 512 + tcs * 64 + d)) * 512 + i0 + jc * 16;
      *(short8*)tp = v0;
      *(short8*)(tp + 8) = v1;
    }
  }
}

// ---------------- K2: fused MFMA pair-attention, 64-row tiles, ring-4 B ----------------
// 192 blocks (= 8 XCD x 24) x 512 threads. A staged in 64KB swizzled LDS.
// R6/R7 A/B showed per-wave latency chain (not wave supply) limits k2 ->
// deepen B-ring to 4 outstanding loads (VGPR 120->~160, still 2 waves/EU).
__global__ __launch_bounds__(512, 2) void k2_mfma(
    const unsigned short* __restrict__ Xm0, const unsigned short* __restrict__ Xm1,
    const unsigned short* __restrict__ Xm2,
    const unsigned short* __restrict__ Bn, const unsigned short* __restrict__ Cn,
    const unsigned short* __restrict__ Bt, const unsigned short* __restrict__ Ct,
    const float* __restrict__ A, const float* __restrict__ Bm,
    const float* __restrict__ rowterm, const float* __restrict__ colterm,
    float* __restrict__ mrow, float* __restrict__ out) {
  __shared__ __align__(16) unsigned char smem[65536];
  unsigned short* A_lds = (unsigned short*)smem;
  unsigned short* P_lds = (unsigned short*)smem;
  float* sm_m = (float*)smem;
  float* sm_l = (float*)(smem + 2048);

  int tid = threadIdx.x;
  int bid0 = blockIdx.x;
  int bid = (bid0 & 7) * 24 + (bid0 >> 3);
  int p = bid >> 6;
  int b = (bid >> 3) & 7;
  int rb = bid & 7;
  int i0 = rb * 64;

  const unsigned short* Xmp = (p == 0) ? Xm0 : ((p == 1) ? Xm1 : Xm2);
  const unsigned short* Yn  = (p == 0) ? Bn : Cn;
  const unsigned short* Yt  = (p == 0) ? Bt : Ct;
  const float* X = (p == 2) ? Bm : A;

  int wc = tid >> 6;
  int lane = tid & 63;
  int n16 = lane & 15, q = lane >> 4;
  int e8 = n16 & 7;

#pragma unroll
  for (int j = 0; j < 8; ++j) {
    int idx = j * 512 + tid;
    int row = idx >> 6;
    int cc = idx & 63;
    short8 v = *(const short8*)(Xmp + ((size_t)(b * LL + i0 + row)) * HH + cc * 8);
    *(short8*)&A_lds[row * 512 + (cc ^ (row & 7)) * 8] = v;
  }
  __syncthreads();

  const unsigned short* br0 = Yn + ((size_t)(b * LL + wc * 64 + n16)) * HH + q * 8;
  const unsigned short* br1 = br0 + 16 * HH;
  const unsigned short* br2 = br0 + 32 * HH;
  const unsigned short* br3 = br0 + 48 * HH;

  floatx4 acc[4][4] = {};
  short8 Ax0[4], Ax1[4], Bx0[4], Bx1[4], Bx2[4], Bx3[4];

#define LA(AF, kk) do { int ch_ = (((kk) * 4 + q) ^ e8) * 8; \
    AF[0] = *(const short8*)&A_lds[(n16)      * 512 + ch_]; \
    AF[1] = *(const short8*)&A_lds[(16 + n16) * 512 + ch_]; \
    AF[2] = *(const short8*)&A_lds[(32 + n16) * 512 + ch_]; \
    AF[3] = *(const short8*)&A_lds[(48 + n16) * 512 + ch_]; } while (0)
#define LB1(BF, kk) do { const int k0_ = (kk) * 32; \
    BF[0] = *(const short8*)(br0 + k0_); \
    BF[1] = *(const short8*)(br1 + k0_); \
    BF[2] = *(const short8*)(br2 + k0_); \
    BF[3] = *(const short8*)(br3 + k0_); } while (0)
#define MF1(AF, BF) do { \
    acc[0][0]=MM(AF[0],BF[0],acc[0][0],0,0,0); acc[0][1]=MM(AF[0],BF[1],acc[0][1],0,0,0); \
    acc[0][2]=MM(AF[0],BF[2],acc[0][2],0,0,0); acc[0][3]=MM(AF[0],BF[3],acc[0][3],0,0,0); \
    acc[1][0]=MM(AF[1],BF[0],acc[1][0],0,0,0); acc[1][1]=MM(AF[1],BF[1],acc[1][1],0,0,0); \
    acc[1][2]=MM(AF[1],BF[2],acc[1][2],0,0,0); acc[1][3]=MM(AF[1],BF[3],acc[1][3],0,0,0); \
    acc[2][0]=MM(AF[2],BF[0],acc[2][0],0,0,0); acc[2][1]=MM(AF[2],BF[1],acc[2][1],0,0,0); \
    acc[2][2]=MM(AF[2],BF[2],acc[2][2],0,0,0); acc[2][3]=MM(AF[2],BF[3],acc[2][3],0,0,0); \
    acc[3][0]=MM(AF[3],BF[0],acc[3][0],0,0,0); acc[3][1]=MM(AF[3],BF[1],acc[3][1],0,0,0); \
    acc[3][2]=MM(AF[3],BF[2],acc[3][2],0,0,0); acc[3][3]=MM(AF[3],BF[3],acc[3][3],0,0,0); } while (0)

  LB1(Bx0, 0); LB1(Bx1, 1); LB1(Bx2, 2); LB1(Bx3, 3); LA(Ax0, 0); LA(Ax1, 1); SB();
  MF1(Ax0, Bx0); LA(Ax0, 2);  LB1(Bx0, 4);  SB();
  MF1(Ax1, Bx1); LA(Ax1, 3);  LB1(Bx1, 5);  SB();
  MF1(Ax0, Bx2); LA(Ax0, 4);  LB1(Bx2, 6);  SB();
  MF1(Ax1, Bx3); LA(Ax1, 5);  LB1(Bx3, 7);  SB();
  MF1(Ax0, Bx0); LA(Ax0, 6);  LB1(Bx0, 8);  SB();
  MF1(Ax1, Bx1); LA(Ax1, 7);  LB1(Bx1, 9);  SB();
  MF1(Ax0, Bx2); LA(Ax0, 8);  LB1(Bx2, 10); SB();
  MF1(Ax1, Bx3); LA(Ax1, 9);  LB1(Bx3, 11); SB();
  MF1(Ax0, Bx0); LA(Ax0, 10); LB1(Bx0, 12); SB();
  MF1(Ax1, Bx1); LA(Ax1, 11); LB1(Bx1, 13); SB();
  MF1(Ax0, Bx2); LA(Ax0, 12); LB1(Bx2, 14); SB();
  MF1(Ax1, Bx3); LA(Ax1, 13); LB1(Bx3, 15); SB();
  MF1(Ax0, Bx0); LA(Ax0, 14); SB();
  MF1(Ax1, Bx1); LA(Ax1, 15); SB();
  MF1(Ax0, Bx2); SB();
  MF1(Ax1, Bx3);
#undef LA
#undef LB1
#undef MF1

  __syncthreads();

  float rtv[4][4], ctv[4], mh[4][4], ml[4][4], rinv[4][4];
  {
    const float* rtp = rowterm + (p * BB + b) * LL + i0 + q * 4;
#pragma unroll
    for (int rt = 0; rt < 4; ++rt)
#pragma unroll
      for (int r = 0; r < 4; ++r) rtv[rt][r] = rtp[rt * 16 + r];
    const float* ctp = colterm + (p * BB + b) * LL + wc * 64 + n16;
#pragma unroll
    for (int f = 0; f < 4; ++f) ctv[f] = ctp[f * 16];
  }
#pragma unroll
  for (int rt = 0; rt < 4; ++rt)
#pragma unroll
    for (int r = 0; r < 4; ++r) {
      float m = -1e30f;
#pragma unroll
      for (int f = 0; f < 4; ++f) {
        float v = acc[rt][f][r] + rtv[rt][r] + ctv[f];
        acc[rt][f][r] = v;
        m = fmaxf(m, v);
      }
      m = fmaxf(m, __shfl_xor(m, 1, 64));
      m = fmaxf(m, __shfl_xor(m, 2, 64));
      m = fmaxf(m, __shfl_xor(m, 4, 64));
      m = fmaxf(m, __shfl_xor(m, 8, 64));
      mh[rt][r] = m;
    }
  if (n16 == 0) {
#pragma unroll
    for (int rt = 0; rt < 4; ++rt)
#pragma unroll
      for (int r = 0; r < 4; ++r) sm_m[wc * 64 + rt * 16 + q * 4 + r] = mh[rt][r];
  }
  __syncthreads();
#pragma unroll
  for (int rt = 0; rt < 4; ++rt)
#pragma unroll
    for (int r = 0; r < 4; ++r) {
      float m = mh[rt][r];
#pragma unroll
      for (int k = 0; k < 8; ++k) m = fmaxf(m, sm_m[k * 64 + rt * 16 + q * 4 + r]);
      mh[rt][r] = m;
      float l = 0.f;
#pragma unroll
      for (int f = 0; f < 4; ++f) {
        float pv = __expf(acc[rt][f][r] - m);
        acc[rt][f][r] = pv;
        l += pv;
      }
      l += __shfl_xor(l, 1, 64);
      l += __shfl_xor(l, 2, 64);
      l += __shfl_xor(l, 4, 64);
      l += __shfl_xor(l, 8, 64);
      ml[rt][r] = l;
    }
  if (n16 == 0) {
#pragma unroll
    for (int rt = 0; rt < 4; ++rt)
#pragma unroll
      for (int r = 0; r < 4; ++r) sm_l[wc * 64 + rt * 16 + q * 4 + r] = ml[rt][r];
    if (wc == 0) {
#pragma unroll
      for (int rt = 0; rt < 4; ++rt)
#pragma unroll
        for (int r = 0; r < 4; ++r)
          mrow[(p * BB + b) * LL + i0 + rt * 16 + q * 4 + r] = mh[rt][r];
    }
  }
  __syncthreads();
#pragma unroll
  for (int rt = 0; rt < 4; ++rt)
#pragma unroll
    for (int r = 0; r < 4; ++r) {
      float lf = 0.f;
#pragma unroll
      for (int k = 0; k < 8; ++k) lf += sm_l[k * 64 + rt * 16 + q * 4 + r];
      rinv[rt][r] = 1.f / lf;
    }
  __syncthreads();

#pragma unroll
  for (int f = 0; f < 4; ++f) {
    int c = wc * 8 + f * 2 + (n16 >> 3);
#pragma unroll
    for (int rt = 0; rt < 4; ++rt)
#pragma unroll
      for (int r = 0; r < 4; ++r) {
        int row = rt * 16 + q * 4 + r;
        int pc = c ^ (row & 7);
        P_lds[row * 512 + pc * 8 + e8] = f2bf(acc[rt][f][r]);
      }
  }
  __syncthreads();

  const unsigned short* tr0 = Yt + ((size_t)(b * LL + wc * 64 + n16)) * HH + q * 8;
  const unsigned short* tr1 = tr0 + 16 * HH;
  const unsigned short* tr2 = tr0 + 32 * HH;
  const unsigned short* tr3 = tr0 + 48 * HH;

  floatx4 oacc[4][4] = {};
  short8 Px0[4], Px1[4], By0[4], By1[4], By2[4], By3[4];

#define LP(PF, kj) do { int ch_ = (((kj) * 4 + q) ^ e8) * 8; \
    PF[0] = *(const short8*)&P_lds[(n16)      * 512 + ch_]; \
    PF[1] = *(const short8*)&P_lds[(16 + n16) * 512 + ch_]; \
    PF[2] = *(const short8*)&P_lds[(32 + n16) * 512 + ch_]; \
    PF[3] = *(const short8*)&P_lds[(48 + n16) * 512 + ch_]; } while (0)
#define LB2(BF, kj) do { const int j0_ = (kj) * 32; \
    BF[0] = *(const short8*)(tr0 + j0_); \
    BF[1] = *(const short8*)(tr1 + j0_); \
    BF[2] = *(const short8*)(tr2 + j0_); \
    BF[3] = *(const short8*)(tr3 + j0_); } while (0)
#define MF2(PF, BF) do { \
    oacc[0][0]=MM(PF[0],BF[0],oacc[0][0],0,0,0); oacc[0][1]=MM(PF[0],BF[1],oacc[0][1],0,0,0); \
    oacc[0][2]=MM(PF[0],BF[2],oacc[0][2],0,0,0); oacc[0][3]=MM(PF[0],BF[3],oacc[0][3],0,0,0); \
    oacc[1][0]=MM(PF[1],BF[0],oacc[1][0],0,0,0); oacc[1][1]=MM(PF[1],BF[1],oacc[1][1],0,0,0); \
    oacc[1][2]=MM(PF[1],BF[2],oacc[1][2],0,0,0); oacc[1][3]=MM(PF[1],BF[3],oacc[1][3],0,0,0); \
    oacc[2][0]=MM(PF[2],BF[0],oacc[2][0],0,0,0); oacc[2][1]=MM(PF[2],BF[1],oacc[2][1],0,0,0); \
    oacc[2][2]=MM(PF[2],BF[2],oacc[2][2],0,0,0); oacc[2][3]=MM(PF[2],BF[3],oacc[2][3],0,0,0); \
    oacc[3][0]=MM(PF[3],BF[0],oacc[3][0],0,0,0); oacc[3][1]=MM(PF[3],BF[1],oacc[3][1],0,0,0); \
    oacc[3][2]=MM(PF[3],BF[2],oacc[3][2],0,0,0); oacc[3][3]=MM(PF[3],BF[3],oacc[3][3],0,0,0); } while (0)

  LB2(By0, 0); LB2(By1, 1); LB2(By2, 2); LB2(By3, 3); LP(Px0, 0); LP(Px1, 1); SB();
  MF2(Px0, By0); LP(Px0, 2);  LB2(By0, 4);  SB();
  MF2(Px1, By1); LP(Px1, 3);  LB2(By1, 5);  SB();
  MF2(Px0, By2); LP(Px0, 4);  LB2(By2, 6);  SB();
  MF2(Px1, By3); LP(Px1, 5);  LB2(By3, 7);  SB();
  MF2(Px0, By0); LP(Px0, 6);  LB2(By0, 8);  SB();
  MF2(Px1, By1); LP(Px1, 7);  LB2(By1, 9);  SB();
  MF2(Px0, By2); LP(Px0, 8);  LB2(By2, 10); SB();
  MF2(Px1, By3); LP(Px1, 9);  LB2(By3, 11); SB();
  MF2(Px0, By0); LP(Px0, 10); LB2(By0, 12); SB();
  MF2(Px1, By1); LP(Px1, 11); LB2(By1, 13); SB();
  MF2(Px0, By2); LP(Px0, 12); LB2(By2, 14); SB();
  MF2(Px1, By3); LP(Px1, 13); LB2(By3, 15); SB();
  MF2(Px0, By0); LP(Px0, 14); SB();
  MF2(Px1, By1); LP(Px1, 15); SB();
  MF2(Px0, By2); SB();
  MF2(Px1, By3);
#undef LP
#undef LB2
#undef MF2

  int secoff, colbase;
  if      (p == 0) { secoff = 0;   colbase = 512;  }
  else if (p == 1) { secoff = 0;   colbase = 1024; }
  else             { secoff = 512; colbase = 1024; }

#pragma unroll
  for (int f = 0; f < 4; ++f) {
    int d = wc * 64 + f * 16 + n16;
#pragma unroll
    for (int rt = 0; rt < 4; ++rt)
#pragma unroll
      for (int r = 0; r < 4; ++r) {
        int ig = i0 + rt * 16 + q * 4 + r;
        float val = oacc[rt][f][r] * rinv[rt][r];
        size_t ob = ((size_t)b * 1536 + secoff + ig) * 2560;
        out[ob + colbase + d] = val;
        out[ob + colbase + 1024 + d] = X[((size_t)b * LL + ig) * HH + d] * val;
      }
  }
}

// ---------------- K3: beta softmax + weighted row-sum (192 blocks x 512) ----------------
__global__ __launch_bounds__(512) void k3_beta(
    const float* __restrict__ A, const float* __restrict__ Bm,
    const float* __restrict__ mrow, float* __restrict__ vvec) {
  __shared__ float red[512];
  __shared__ float beta[LL];
  __shared__ float s_inv;
  int blk = blockIdx.x;           // 192
  int p = blk >> 6;
  int rem2 = blk & 63;
  int b = rem2 >> 3;
  int dch = rem2 & 7;
  int tid = threadIdx.x;          // 0..511
  const float* m = mrow + (p * BB + b) * LL;
  red[tid] = m[tid];
  __syncthreads();
  for (int off = 256; off; off >>= 1) {
    if (tid < off) red[tid] = fmaxf(red[tid], red[tid + off]);
    __syncthreads();
  }
  float mx = red[0];
  __syncthreads();
  float e0 = __expf(m[tid] - mx);
  beta[tid] = e0;
  red[tid] = e0;
  __syncthreads();
  for (int off = 256; off; off >>= 1) {
    if (tid < off) red[tid] += red[tid + off];
    __syncthreads();
  }
  if (tid == 0) s_inv = 1.f / red[0];
  __syncthreads();
  const float* Xb = ((p == 2) ? Bm : A) + (size_t)b * LL * HH;
  int d = dch * 64 + (tid & 63);
  int ig = tid >> 6;              // 8 groups of 64 rows
  float acc = 0.f;
#pragma unroll 4
  for (int i2 = ig * 64; i2 < ig * 64 + 64; ++i2)
    acc += beta[i2] * Xb[(size_t)i2 * HH + d];
  red[tid] = acc;
  __syncthreads();
  if (tid < 64) {
    float s = 0.f;
#pragma unroll
    for (int k = 0; k < 8; ++k) s += red[tid + k * 64];
    vvec[(p * BB + b) * HH + dch * 64 + tid] = s * s_inv;
  }
}

// ---------------- K4: finalize (9 slices incl. copies), float4 full-line writes ----------------
__global__ __launch_bounds__(256) void k4_finalize(
    const float* __restrict__ A, const float* __restrict__ Bm, const float* __restrict__ C,
    const float* __restrict__ vvec, float* __restrict__ out) {
  unsigned int idx = blockIdx.x * 256 + threadIdx.x;   // 4718592 threads
  int f4 = idx & 127;
  int i  = (idx >> 7) & 511;
  unsigned int ub = idx >> 16;
  unsigned int u = ub % 9;
  unsigned int b = ub / 9;
  int sec, slice;
  if (u == 0)      { sec = 0; slice = 0; }
  else if (u <= 3) { sec = 1; slice = (u == 1) ? 0 : (u == 2 ? 1 : 3); }
  else             { sec = 2; slice = (int)u - 4; }
  int cc = f4 * 4;
  const float* enc = sec == 0 ? A : (sec == 1 ? Bm : C);
  float4 val;
  if (slice == 0) {
    val = *(const float4*)(enc + ((size_t)b * LL + i) * HH + cc);
  } else {
    int vp = (sec == 1) ? 0 : ((slice == 1 || slice == 3) ? 1 : 2);
    float4 v = *(const float4*)(vvec + (vp * BB + b) * HH + cc);
    if (slice <= 2) {
      val = v;
    } else {
      float4 e = *(const float4*)(enc + ((size_t)b * LL + i) * HH + cc);
      val.x = e.x * v.x; val.y = e.y * v.y; val.z = e.z * v.z; val.w = e.w * v.w;
    }
  }
  *(float4*)(out + ((size_t)b * 1536 + sec * 512 + i) * 2560 + slice * 512 + cc) = val;
}

extern "C" void kernel_launch(void* const* d_in, const int* in_sizes, int n_in,
                              void* d_out, int out_size, void* d_ws, size_t ws_size,
                              hipStream_t stream) {
  const float* A  = (const float*)d_in[0];
  const float* Bm = (const float*)d_in[1];
  const float* C  = (const float*)d_in[2];
  const float* w0 = (const float*)d_in[3];
  const float* w1 = (const float*)d_in[4];
  const float* w2 = (const float*)d_in[5];
  float* out = (float*)d_out;

  float* wsf = (float*)d_ws;
  float* rowterm = wsf;
  float* colterm = wsf + 12288;
  float* mrow    = wsf + 24576;
  float* vvec    = wsf + 36864;
  unsigned short* wss = (unsigned short*)(wsf + 49152);
  const size_t MSZ = (size_t)BB * LL * HH;     // 2,097,152
  unsigned short* Bn  = wss;
  unsigned short* Cn  = wss + MSZ;
  unsigned short* Bt  = wss + 2 * MSZ;
  unsigned short* Ct  = wss + 3 * MSZ;
  unsigned short* Xm0 = wss + 4 * MSZ;
  unsigned short* Xm1 = wss + 5 * MSZ;
  unsigned short* Xm2 = wss + 6 * MSZ;

  kP2<<<192, 512, 0, stream>>>(A, Bm, C, w0, w1, w2, Xm0, Xm1, Xm2, Bn, Cn,
                               Bt, Ct, rowterm, colterm);
  k2_mfma<<<192, 512, 0, stream>>>(Xm0, Xm1, Xm2, Bn, Cn, Bt, Ct, A, Bm,
                                   rowterm, colterm, mrow, out);
  k3_beta<<<192, 512, 0, stream>>>(A, Bm, mrow, vvec);
  k4_finalize<<<18432, 256, 0, stream>>>(A, Bm, C, vvec, out);
}